// Round 1
// baseline (31.342 us; speedup 1.0000x reference)
//
#include <hip/hip_runtime.h>

#define NN 1024
#define DIM 64

// ---------------------------------------------------------------------------
// K1: per-row pos/neg sums of graph, c1/c2, base = t1 + t3, u1 = relu(base),
//     per-block column partial sums of u1.
// grid 64 x block 256; each block owns 16 rows.
// ---------------------------------------------------------------------------
__global__ __launch_bounds__(256) void k_pre(
    const float* __restrict__ x, const float* __restrict__ graph,
    const float* __restrict__ W1, const float* __restrict__ W3,
    const float* __restrict__ W4,
    float* __restrict__ base, float* __restrict__ u1, float* __restrict__ p1)
{
    __shared__ float ppos[16], pneg[16];
    __shared__ float c1[DIM], c2[DIM], w1s[DIM], w4s[DIM];
    __shared__ float pcol[4][DIM];

    const int t = threadIdx.x;
    const int lane = t & 63;
    const int wave = t >> 6;
    const int b = blockIdx.x;

    if (t < DIM) { w1s[t] = W1[t]; w4s[t] = W4[t]; }
    __syncthreads();

    // ---- row sums: wave w handles rows w*4 + p ----
    for (int p = 0; p < 4; ++p) {
        const int rloc = wave * 4 + p;
        const int i = b * 16 + rloc;
        const float* row = graph + (size_t)i * NN;
        float pos = 0.f, neg = 0.f;
        #pragma unroll
        for (int k = 0; k < 4; ++k) {
            float4 g = *reinterpret_cast<const float4*>(row + 4 * lane + 256 * k);
            pos += fmaxf(g.x, 0.f) + fmaxf(g.y, 0.f) + fmaxf(g.z, 0.f) + fmaxf(g.w, 0.f);
            neg += fminf(g.x, 0.f) + fminf(g.y, 0.f) + fminf(g.z, 0.f) + fminf(g.w, 0.f);
        }
        #pragma unroll
        for (int m = 32; m >= 1; m >>= 1) {
            pos += __shfl_xor(pos, m, 64);
            neg += __shfl_xor(neg, m, 64);
        }
        if (lane == 0) { ppos[rloc] = pos; pneg[rloc] = neg; }
    }

    // ---- c1[d] = sum_e W3[d,e]*relu(W4[e]); c2[d] = sum_e W3[d,e]*min(W4[e],0) ----
    if (t < DIM) {
        float a1 = 0.f, a2 = 0.f;
        const float* w3r = W3 + t * DIM;
        #pragma unroll 8
        for (int e = 0; e < DIM; ++e) {
            const float w4 = w4s[e];
            a1 += w3r[e] * fmaxf(w4, 0.f);
            a2 += w3r[e] * fminf(w4, 0.f);
        }
        c1[t] = a1; c2[t] = a2;
    }
    __syncthreads();

    // ---- base + u1 + column partials ----
    float pacc = 0.f;
    for (int p = 0; p < 4; ++p) {
        const int rloc = wave * 4 + p;
        const int i = b * 16 + rloc;
        const float bse = x[i] * w1s[lane] + ppos[rloc] * c1[lane] + pneg[rloc] * c2[lane];
        const float u = fmaxf(bse, 0.f);
        base[(size_t)i * DIM + lane] = bse;
        u1[(size_t)i * DIM + lane] = u;
        pacc += u;
    }
    pcol[wave][lane] = pacc;
    __syncthreads();
    if (t < DIM)
        p1[b * DIM + t] = pcol[0][t] + pcol[1][t] + pcol[2][t] + pcol[3][t];
}

// ---------------------------------------------------------------------------
// K2: one structure2vec round.
//   summ = sum of per-block partials; qs = W2 @ summ;
//   u'[i,:] = relu(base[i,:] + qs - W2 @ u[i,:]); emit new partials.
// grid 64 x block 256; each block owns 16 rows.
// ---------------------------------------------------------------------------
__global__ __launch_bounds__(256) void k_round(
    const float* __restrict__ uSrc, const float* __restrict__ pSrc,
    const float* __restrict__ base, const float* __restrict__ W2,
    float* __restrict__ uDst, float* __restrict__ pDst)
{
    __shared__ float w2t[DIM * 65];     // w2t[e*65+d] = W2[d*DIM+e]  (pad -> 2-way banks, free)
    __shared__ float uloc[16 * DIM];
    __shared__ float sparts[4 * DIM];
    __shared__ float summ[DIM];
    __shared__ float qs[DIM];
    __shared__ float pcol[4][DIM];

    const int t = threadIdx.x;
    const int lane = t & 63;
    const int wave = t >> 6;
    const int b = blockIdx.x;

    // load W2 transposed into LDS
    #pragma unroll
    for (int k = 0; k < 16; ++k) {
        const int idx = t + 256 * k;
        const int d = idx >> 6, e = idx & 63;
        w2t[e * 65 + d] = W2[idx];
    }
    // reduce per-block partials (64 blocks x 64 dims)
    {
        float s = 0.f;
        #pragma unroll
        for (int k = 0; k < 16; ++k)
            s += pSrc[(wave + 4 * k) * DIM + lane];
        sparts[wave * DIM + lane] = s;
    }
    // stage this block's 16 rows of u
    #pragma unroll
    for (int k = 0; k < 4; ++k) {
        const int idx = t + 256 * k;
        uloc[idx] = uSrc[(size_t)b * 16 * DIM + idx];
    }
    __syncthreads();
    if (t < DIM)
        summ[t] = sparts[t] + sparts[DIM + t] + sparts[2 * DIM + t] + sparts[3 * DIM + t];
    __syncthreads();
    if (t < DIM) {
        float q = 0.f;
        #pragma unroll 8
        for (int e = 0; e < DIM; ++e)
            q += w2t[e * 65 + t] * summ[e];
        qs[t] = q;
    }
    __syncthreads();

    float pacc = 0.f;
    for (int p = 0; p < 4; ++p) {
        const int rloc = wave * 4 + p;
        const int i = b * 16 + rloc;
        float acc = 0.f;
        #pragma unroll 8
        for (int e = 0; e < DIM; ++e)
            acc += w2t[e * 65 + lane] * uloc[rloc * DIM + e];
        const float u = fmaxf(base[(size_t)i * DIM + lane] + qs[lane] - acc, 0.f);
        uDst[(size_t)i * DIM + lane] = u;
        pacc += u;
    }
    pcol[wave][lane] = pacc;
    __syncthreads();
    if (t < DIM)
        pDst[b * DIM + t] = pcol[0][t] + pcol[1][t] + pcol[2][t] + pcol[3][t];
}

// ---------------------------------------------------------------------------
// K3: su = sum_i u4[i,:]; out = W5 . relu([W6@su ; W7@u4[v]])
// ---------------------------------------------------------------------------
__global__ __launch_bounds__(64) void k_final(
    const float* __restrict__ u4, const float* __restrict__ p4,
    const float* __restrict__ W5, const float* __restrict__ W6,
    const float* __restrict__ W7, const int* __restrict__ vptr,
    float* __restrict__ out)
{
    __shared__ float su[DIM], uv[DIM];
    const int t = threadIdx.x;   // 64 threads
    const int v = vptr[0];
    float s = 0.f;
    #pragma unroll 8
    for (int bb = 0; bb < 64; ++bb) s += p4[bb * DIM + t];
    su[t] = s;
    uv[t] = u4[(size_t)v * DIM + t];
    __syncthreads();
    float h1 = 0.f, h2 = 0.f;
    const float* w6r = W6 + t * DIM;
    const float* w7r = W7 + t * DIM;
    #pragma unroll 8
    for (int e = 0; e < DIM; ++e) {
        h1 += w6r[e] * su[e];
        h2 += w7r[e] * uv[e];
    }
    float val = W5[t] * fmaxf(h1, 0.f) + W5[DIM + t] * fmaxf(h2, 0.f);
    #pragma unroll
    for (int m = 32; m >= 1; m >>= 1) val += __shfl_xor(val, m, 64);
    if (t == 0) out[0] = val;
}

extern "C" void kernel_launch(void* const* d_in, const int* in_sizes, int n_in,
                              void* d_out, int out_size, void* d_ws, size_t ws_size,
                              hipStream_t stream) {
    const float* x     = (const float*)d_in[0];
    const float* graph = (const float*)d_in[1];
    const float* W1    = (const float*)d_in[2];
    const float* W2    = (const float*)d_in[3];
    const float* W3    = (const float*)d_in[4];
    const float* W4    = (const float*)d_in[5];
    const float* W5    = (const float*)d_in[6];
    const float* W6    = (const float*)d_in[7];
    const float* W7    = (const float*)d_in[8];
    const int*   vptr  = (const int*)d_in[9];
    float* out = (float*)d_out;

    float* ws   = (float*)d_ws;
    float* base = ws;                         // 65536 f32
    float* uA   = ws + 65536;                 // 65536
    float* uB   = ws + 2 * 65536;             // 65536
    float* pA   = ws + 3 * 65536;             // 4096
    float* pB   = ws + 3 * 65536 + 4096;      // 4096   (total 800 KB)

    k_pre  <<<64, 256, 0, stream>>>(x, graph, W1, W3, W4, base, uA, pA);
    k_round<<<64, 256, 0, stream>>>(uA, pA, base, W2, uB, pB);   // round 2
    k_round<<<64, 256, 0, stream>>>(uB, pB, base, W2, uA, pA);   // round 3
    k_round<<<64, 256, 0, stream>>>(uA, pA, base, W2, uB, pB);   // round 4
    k_final<<<1, 64, 0, stream>>>(uB, pB, W5, W6, W7, vptr, out);
}